// Round 23
// baseline (260.753 us; speedup 1.0000x reference)
//
#include <hip/hip_runtime.h>
#include <hip/hip_bf16.h>

// EarthSpecificBlock, MI355X round 23 (r22 base, 240.1us):
//  - Ql/Kl/Pbw row stride 40 -> 44 ushorts: us4 epilogue/P-pack stores were
//    lumpy (li period 8, banks up to 6-way); stride 44 -> all 16 li banks
//    distinct -> uniform 4-way (HW floor for 8B/lane). b128 reads stay free.
//  - bias_r tiles prefetched into registers BEFORE Phase A (they feed the
//    S-MFMA C-operand; L2 latency now hides under 108 Phase-A MFMAs).
//  - everything else identical to r22.

typedef __attribute__((ext_vector_type(8))) short bfrag;          // 8 bf16 (4 VGPR)
typedef __attribute__((ext_vector_type(4))) float f32x4;          // C/D frag
typedef __attribute__((ext_vector_type(4))) unsigned short us4;   // 8B of bf16
typedef __attribute__((ext_vector_type(8))) unsigned short us8;   // 16B of bf16

#define VSTR 172   // Vt row stride (ushorts)
#define QSTR 44    // Ql/Kl/Pbw row stride (ushorts); 40 was lumpy-4-way

__device__ __forceinline__ unsigned short f2bf(float f) {
    __hip_bfloat16 h = __float2bfloat16(f);     // HW RNE cvt
    unsigned short s;
    __builtin_memcpy(&s, &h, 2);
    return s;
}
__device__ __forceinline__ us4 pack4(float a, float b, float c, float d) {
    us4 o;
    o[0] = f2bf(a); o[1] = f2bf(b); o[2] = f2bf(c); o[3] = f2bf(d);
    return o;
}
__device__ __forceinline__ float bf2f(unsigned short s) {
    return __builtin_bit_cast(float, ((unsigned int)s) << 16);
}
__device__ __forceinline__ int token_of(int iw, int n) {
    int wi = iw % 15, hi = (iw / 15) % 16, zi = iw / 240;
    int ww = n % 12, hh = (n / 12) % 6, zz = n / 72;
    return ((zi * 2 + zz) * 96 + hi * 6 + hh) * 180 + wi * 12 + ww;
}

#define INV_SCALE 0.17677669529663687f   // 1/sqrt(32)

// ---- setup (merged): blocks 0..431 -> wt (Q rows pre-scaled);
// 432..575 -> wp_t; 576..719 -> wm_t. ----
__global__ __launch_bounds__(256) void wconv_all(const float* __restrict__ w_qkv,
                                                 const float* __restrict__ w_proj,
                                                 const float* __restrict__ w_mlp,
                                                 unsigned short* __restrict__ wt,
                                                 unsigned short* __restrict__ wp_t,
                                                 unsigned short* __restrict__ wm_t) {
    int b = blockIdx.x;
    if (b < 432) {
        int id = b * 256 + threadIdx.x;            // 110592
        if (id >= 110592) return;
        int k = id / 576, c = id - k * 576;
        float v = w_qkv[id];
        if (c < 192) v *= INV_SCALE;
        wt[c * 192 + k] = f2bf(v);
    } else {
        int y = (b - 432) / 144;                   // 0: wp, 1: wm
        int id = ((b - 432) - y * 144) * 256 + threadIdx.x;   // 36864
        if (id >= 36864) return;
        const float* src = y ? w_mlp : w_proj;
        unsigned short* dst = y ? wm_t : wp_t;
        int n = id / 192, k = id - n * 192;
        dst[id] = f2bf(src[(size_t)k * 192 + n]);
    }
}

// ---- bias_r[th][i][j] = bias_table[posidx(i,j)][t][h] (bf16) ----
__global__ __launch_bounds__(256) void bias_reorg(const float* __restrict__ bias_table,
                                                  unsigned short* __restrict__ bias_r) {
    __shared__ unsigned short T[384][68];
    int p0 = blockIdx.x * 64;                      // 324 blocks x 64 pairs
    int tid = threadIdx.x;
    for (int e = tid; e < 64 * 384; e += 256) {
        int pl = e / 384, th = e - pl * 384;
        int pair = p0 + pl;
        int i = pair / 144, j = pair - i * 144;
        int z1 = i / 72, h1 = (i / 12) % 6, w1 = i % 12;
        int z2 = j / 72, h2 = (j / 12) % 6, w2 = j % 12;
        int idx = (z1 + 2 * z2) * 828 + (h1 + 6 * h2) * 23 + (w1 - w2 + 11);
        T[th][pl] = f2bf(bias_table[(size_t)idx * 384 + th]);
    }
    __syncthreads();
    for (int e = tid; e < 384 * 16; e += 256) {
        int th = e >> 4, pc = e & 15;
        *(us4*)&bias_r[(size_t)th * 20736 + p0 + pc * 4] = *(const us4*)&T[th][pc * 4];
    }
}

// ---- Fused QKV + Attention, one block per WINDOW, 6 waves (r15/r18 shell).
// Xw staged from fp32 x (cvt in staging); 3 rounds x 2 heads; waves (tri,tw):
// tw = 0:Q 1:K 2:V. Phase A swapped operands; S MFMA takes bias as C-operand
// (prefetched into regs during Phase A). Phase B = attention body. ----
__global__ __launch_bounds__(384) void qkattn(const float* __restrict__ x,
                                              const unsigned short* __restrict__ wt,
                                              const float* __restrict__ b_qkv,
                                              const unsigned short* __restrict__ bias_r,
                                              unsigned short* __restrict__ o_ws) {
    __shared__ __align__(16) unsigned short Xw[144 * 200];      // 57600 B
    __shared__ __align__(16) unsigned short Ql[2][144 * QSTR];  // 25344 B (+Pb alias)
    __shared__ __align__(16) unsigned short Kl[2][144 * QSTR];  // 25344 B
    __shared__ __align__(16) unsigned short Vt[2][32 * VSTR];   // 22016 B
    int tid = threadIdx.x;
    int iw = blockIdx.x;
    int w = tid >> 6, l = tid & 63, li = l & 15, lg = l >> 4;
    int tri = w / 3, tw = w - tri * 3;

    // stage window x fp32 -> bf16 into Xw: 3456 chunks of 8 elems, 9/thread
#pragma unroll
    for (int i = 0; i < 9; ++i) {
        int idx = tid + i * 384;                   // < 3456 = 144*24
        int r = idx / 24, g = idx - r * 24;
        const float* xp = &x[(size_t)token_of(iw, r) * 192 + g * 8];
        float4 v0 = *(const float4*)xp;
        float4 v1 = *(const float4*)(xp + 4);
        us4 a = pack4(v0.x, v0.y, v0.z, v0.w);
        us4 b = pack4(v1.x, v1.y, v1.z, v1.w);
        *(us4*)&Xw[r * 200 + g * 8] = a;
        *(us4*)&Xw[r * 200 + g * 8 + 4] = b;
    }
    __syncthreads();

    int it0 = tw * 3;
    for (int rnd = 0; rnd < 3; ++rnd) {
        int h = rnd * 2 + tri;

        // prefetch bias tiles for THIS round's S phase (consumed post-barrier;
        // L2 latency hides under Phase A's 108 MFMAs)
        const unsigned short* bp = bias_r + ((size_t)((iw & 63) * 6 + h)) * 20736;
        us4 bvv[9][3];
#pragma unroll
        for (int jt = 0; jt < 9; ++jt)
#pragma unroll
            for (int itl = 0; itl < 3; ++itl) {
                int i = (it0 + itl) * 16 + li;
                int j0 = jt * 16 + lg * 4;
                bvv[jt][itl] = *(const us4*)&bp[i * 144 + j0];
            }

        // ---- Phase A: D[c][t] = sum_k W[k][c] X[t][k] (swapped operands) ----
        int wrow = tw * 192 + h * 32;
        f32x4 acc[2][9];
#pragma unroll
        for (int ct = 0; ct < 2; ++ct)
#pragma unroll
            for (int tt = 0; tt < 9; ++tt) acc[ct][tt] = (f32x4){0.f, 0.f, 0.f, 0.f};
#pragma unroll
        for (int kk = 0; kk < 6; ++kk) {
            int k0 = kk * 32 + lg * 8;
            bfrag wf[2];
#pragma unroll
            for (int ct = 0; ct < 2; ++ct)
                wf[ct] = *(const bfrag*)&wt[(size_t)(wrow + ct * 16 + li) * 192 + k0];
#pragma unroll
            for (int tt = 0; tt < 9; ++tt) {
                bfrag xf = *(const bfrag*)&Xw[(tt * 16 + li) * 200 + k0];
                acc[0][tt] = __builtin_amdgcn_mfma_f32_16x16x32_bf16(wf[0], xf, acc[0][tt], 0, 0, 0);
                acc[1][tt] = __builtin_amdgcn_mfma_f32_16x16x32_bf16(wf[1], xf, acc[1][tt], 0, 0, 0);
            }
        }
        // lane holds D[c = ct*16 + lg*4 + r][t = tt*16 + li]
        if (tw < 2) {
            unsigned short* dst = (tw == 0) ? &Ql[tri][0] : &Kl[tri][0];
            float bscale = (tw == 0) ? INV_SCALE : 1.0f;   // Q bias pre-scaled too
#pragma unroll
            for (int ct = 0; ct < 2; ++ct) {
                float4 bq = *(const float4*)&b_qkv[tw * 192 + h * 32 + ct * 16 + lg * 4];
                bq.x *= bscale; bq.y *= bscale; bq.z *= bscale; bq.w *= bscale;
#pragma unroll
                for (int tt = 0; tt < 9; ++tt) {
                    us4 o = pack4(acc[ct][tt][0] + bq.x, acc[ct][tt][1] + bq.y,
                                  acc[ct][tt][2] + bq.z, acc[ct][tt][3] + bq.w);
                    *(us4*)&dst[(tt * 16 + li) * QSTR + ct * 16 + lg * 4] = o;
                }
            }
        } else {
#pragma unroll
            for (int ct = 0; ct < 2; ++ct) {
                float4 bq = *(const float4*)&b_qkv[2 * 192 + h * 32 + ct * 16 + lg * 4];
                float bqa[4] = {bq.x, bq.y, bq.z, bq.w};
#pragma unroll
                for (int tt = 0; tt < 9; ++tt)
#pragma unroll
                    for (int r = 0; r < 4; ++r)
                        Vt[tri][(ct * 16 + lg * 4 + r) * VSTR + tt * 16 + li] =
                            f2bf(acc[ct][tt][r] + bqa[r]);
            }
            // zero-pad Vt cols 144..159 (this wave owns its tri buffer)
            int d = l >> 1, half = l & 1;
            *(uint4*)&Vt[tri][d * VSTR + 144 + half * 8] = (uint4){0u, 0u, 0u, 0u};
        }
        __syncthreads();

        // ---- Phase B: attention (buffers [tri]) ----
        unsigned short* Pbw = &Ql[tri][(size_t)tw * 48 * QSTR];
        bfrag qf[3];
#pragma unroll
        for (int itl = 0; itl < 3; ++itl)
            qf[itl] = *(const bfrag*)&Ql[tri][((it0 + itl) * 16 + li) * QSTR + lg * 8];

        // S^T = (scaled Q)K^T + bias (prefetched), bias as MFMA C-operand
        f32x4 S[9][3];
#pragma unroll
        for (int jt = 0; jt < 9; ++jt) {
            bfrag kf = *(const bfrag*)&Kl[tri][(jt * 16 + li) * QSTR + lg * 8];
#pragma unroll
            for (int itl = 0; itl < 3; ++itl) {
                us4 bv = bvv[jt][itl];
                f32x4 c;
                c[0] = bf2f(bv[0]); c[1] = bf2f(bv[1]);
                c[2] = bf2f(bv[2]); c[3] = bf2f(bv[3]);
                S[jt][itl] = __builtin_amdgcn_mfma_f32_16x16x32_bf16(kf, qf[itl], c, 0, 0, 0);
            }
        }

        float inv[3];
#pragma unroll
        for (int itl = 0; itl < 3; ++itl) {
            float mx = -3.0e38f;
#pragma unroll
            for (int jt = 0; jt < 9; ++jt)
#pragma unroll
                for (int r = 0; r < 4; ++r) mx = fmaxf(mx, S[jt][itl][r]);
            mx = fmaxf(mx, __shfl_xor(mx, 16));
            mx = fmaxf(mx, __shfl_xor(mx, 32));
            float sum = 0.f;
#pragma unroll
            for (int jt = 0; jt < 9; ++jt)
#pragma unroll
                for (int r = 0; r < 4; ++r) {
                    float e = __expf(S[jt][itl][r] - mx);
                    S[jt][itl][r] = e;
                    sum += e;
                }
            sum += __shfl_xor(sum, 16);
            sum += __shfl_xor(sum, 32);
            inv[itl] = 1.f / sum;
        }

        f32x4 O[2][3];
#pragma unroll
        for (int dt = 0; dt < 2; ++dt)
#pragma unroll
            for (int itl = 0; itl < 3; ++itl) O[dt][itl] = (f32x4){0.f, 0.f, 0.f, 0.f};

        for (int jc = 0; jc < 5; ++jc) {
#pragma unroll
            for (int itl = 0; itl < 3; ++itl) {
                int irow = itl * 16 + li;
#pragma unroll
                for (int half = 0; half < 2; ++half) {
                    int jt = jc * 2 + half;
                    us4 pk;
                    if (jt < 9) {
                        pk = pack4(S[jt][itl][0], S[jt][itl][1], S[jt][itl][2], S[jt][itl][3]);
                    } else {
                        pk = (us4){0, 0, 0, 0};
                    }
                    *(us4*)&Pbw[irow * QSTR + half * 16 + lg * 4] = pk;
                }
            }
            bfrag pf[3], af[2];
#pragma unroll
            for (int itl = 0; itl < 3; ++itl)
                pf[itl] = *(const bfrag*)&Pbw[(itl * 16 + li) * QSTR + lg * 8];
#pragma unroll
            for (int dt = 0; dt < 2; ++dt)
                af[dt] = *(const bfrag*)&Vt[tri][(dt * 16 + li) * VSTR + jc * 32 + lg * 8];
#pragma unroll
            for (int dt = 0; dt < 2; ++dt)
#pragma unroll
                for (int itl = 0; itl < 3; ++itl)
                    O[dt][itl] = __builtin_amdgcn_mfma_f32_16x16x32_bf16(af[dt], pf[itl], O[dt][itl], 0, 0, 0);
        }

#pragma unroll
        for (int itl = 0; itl < 3; ++itl) {
#pragma unroll
            for (int dt = 0; dt < 2; ++dt) {
                us4 ov = pack4(O[dt][itl][0] * inv[itl], O[dt][itl][1] * inv[itl],
                               O[dt][itl][2] * inv[itl], O[dt][itl][3] * inv[itl]);
                *(us4*)&Pbw[(itl * 16 + li) * QSTR + dt * 16 + lg * 4] = ov;
            }
        }
#pragma unroll
        for (int s = 0; s < 3; ++s) {
            int gi = s * 64 + l;
            int row = gi >> 2, g = gi & 3;
            uint4 v = *(const uint4*)&Pbw[row * QSTR + g * 8];
            int t = token_of(iw, it0 * 16 + row);
            *(uint4*)&o_ws[(size_t)t * 192 + h * 32 + g * 8] = v;
        }
        __syncthreads();                           // buffers reusable next round
    }
}

// ---- Fused proj+LN1+res -> mlp+LN2+res. 128 rows/block, 8 waves.
// Whole weight matrix in LDS per GEMM; GEMM1 A direct from global. ----
__global__ __launch_bounds__(512) void mlp_mfma(const unsigned short* __restrict__ o_ws,
                                                const float* __restrict__ x,
                                                const unsigned short* __restrict__ wp_t,
                                                const float* __restrict__ b_proj,
                                                const float* __restrict__ g1,
                                                const float* __restrict__ b1,
                                                const float* __restrict__ g2,
                                                const float* __restrict__ b2,
                                                const unsigned short* __restrict__ wm_t,
                                                const float* __restrict__ b_mlp,
                                                float* __restrict__ out) {
    __shared__ __align__(16) unsigned short Al[128 * 200];  // 51200 B (x1 bf16)
    __shared__ __align__(16) unsigned short Bf[192 * 200];  // 76800 B (full weight [n][k])
    int tid = threadIdx.x;
    int t0 = blockIdx.x * 128;
    int w = tid >> 6, l = tid & 63, li = l & 15, lg = l >> 4;

#pragma unroll
    for (int i = 0; i < 9; ++i) {
        int idx = tid + i * 512;                 // < 4608
        int r = idx / 24, g = idx - r * 24;
        *(uint4*)&Bf[r * 200 + g * 8] = *(const uint4*)&wp_t[(size_t)r * 192 + g * 8];
    }
    __syncthreads();

    f32x4 C[12];
#pragma unroll
    for (int nt = 0; nt < 12; ++nt) C[nt] = (f32x4){0.f, 0.f, 0.f, 0.f};
    for (int kk = 0; kk < 6; ++kk) {
        int k0 = kk * 32 + lg * 8;
        bfrag a = *(const bfrag*)&o_ws[(size_t)(t0 + w * 16 + li) * 192 + k0];
#pragma unroll
        for (int nt = 0; nt < 12; ++nt) {
            bfrag b = *(const bfrag*)&Bf[(nt * 16 + li) * 200 + k0];
            C[nt] = __builtin_amdgcn_mfma_f32_16x16x32_bf16(a, b, C[nt], 0, 0, 0);
        }
    }
    __syncthreads();                             // all waves done reading Bf(wp)

#pragma unroll
    for (int i = 0; i < 9; ++i) {
        int idx = tid + i * 512;
        int r = idx / 24, g = idx - r * 24;
        *(uint4*)&Bf[r * 200 + g * 8] = *(const uint4*)&wm_t[(size_t)r * 192 + g * 8];
    }

    // LN1 + residual; C := x1 (f32); write bf16 x1 into Al (own wave's rows)
    {
        float bp[12], gg[12], bb[12];
#pragma unroll
        for (int nt = 0; nt < 12; ++nt) {
            int f = nt * 16 + li;
            bp[nt] = b_proj[f]; gg[nt] = g1[f]; bb[nt] = b1[f];
        }
#pragma unroll
        for (int r = 0; r < 4; ++r) {
            float s1 = 0.f;
#pragma unroll
            for (int nt = 0; nt < 12; ++nt) s1 += C[nt][r] + bp[nt];
            s1 += __shfl_xor(s1, 1); s1 += __shfl_xor(s1, 2);
            s1 += __shfl_xor(s1, 4); s1 += __shfl_xor(s1, 8);
            float mean = s1 * (1.f / 192.f);
            float s2 = 0.f;
#pragma unroll
            for (int nt = 0; nt < 12; ++nt) {
                float dv = C[nt][r] + bp[nt] - mean; s2 += dv * dv;
            }
            s2 += __shfl_xor(s2, 1); s2 += __shfl_xor(s2, 2);
            s2 += __shfl_xor(s2, 4); s2 += __shfl_xor(s2, 8);
            float rstd = rsqrtf(s2 * (1.f / 192.f) + 1e-5f);
            int row = w * 16 + lg * 4 + r;
            int t = t0 + row;
#pragma unroll
            for (int nt = 0; nt < 12; ++nt) {
                int f = nt * 16 + li;
                float ln = (C[nt][r] + bp[nt] - mean) * rstd * gg[nt] + bb[nt];
                float x1 = x[(size_t)t * 192 + f] + ln;
                C[nt][r] = x1;
                Al[row * 200 + f] = f2bf(x1);
            }
        }
    }
    __syncthreads();                             // Bf(wm) staged; Al x1 ready

    f32x4 C2[12];
#pragma unroll
    for (int nt = 0; nt < 12; ++nt) C2[nt] = (f32x4){0.f, 0.f, 0.f, 0.f};
    for (int kk = 0; kk < 6; ++kk) {
        int k0 = kk * 32 + lg * 8;
        bfrag a = *(const bfrag*)&Al[(w * 16 + li) * 200 + k0];
#pragma unroll
        for (int nt = 0; nt < 12; ++nt) {
            bfrag b = *(const bfrag*)&Bf[(nt * 16 + li) * 200 + k0];
            C2[nt] = __builtin_amdgcn_mfma_f32_16x16x32_bf16(a, b, C2[nt], 0, 0, 0);
        }
    }

    // LN2 + residual -> out (fp32)
    {
        float bp[12], gg[12], bb[12];
#pragma unroll
        for (int nt = 0; nt < 12; ++nt) {
            int f = nt * 16 + li;
            bp[nt] = b_mlp[f]; gg[nt] = g2[f]; bb[nt] = b2[f];
        }
#pragma unroll
        for (int r = 0; r < 4; ++r) {
            float s1 = 0.f;
#pragma unroll
            for (int nt = 0; nt < 12; ++nt) s1 += C2[nt][r] + bp[nt];
            s1 += __shfl_xor(s1, 1); s1 += __shfl_xor(s1, 2);
            s1 += __shfl_xor(s1, 4); s1 += __shfl_xor(s1, 8);
            float mean = s1 * (1.f / 192.f);
            float s2 = 0.f;
#pragma unroll
            for (int nt = 0; nt < 12; ++nt) {
                float dv = C2[nt][r] + bp[nt] - mean; s2 += dv * dv;
            }
            s2 += __shfl_xor(s2, 1); s2 += __shfl_xor(s2, 2);
            s2 += __shfl_xor(s2, 4); s2 += __shfl_xor(s2, 8);
            float rstd = rsqrtf(s2 * (1.f / 192.f) + 1e-5f);
            int t = t0 + w * 16 + lg * 4 + r;
#pragma unroll
            for (int nt = 0; nt < 12; ++nt) {
                int f = nt * 16 + li;
                float ln = (C2[nt][r] + bp[nt] - mean) * rstd * gg[nt] + bb[nt];
                out[(size_t)t * 192 + f] = C[nt][r] + ln;
            }
        }
    }
}

extern "C" void kernel_launch(void* const* d_in, const int* in_sizes, int n_in,
                              void* d_out, int out_size, void* d_ws, size_t ws_size,
                              hipStream_t stream) {
    const float* x          = (const float*)d_in[0];
    const float* w_qkv      = (const float*)d_in[1];
    const float* b_qkv      = (const float*)d_in[2];
    const float* w_proj     = (const float*)d_in[3];
    const float* b_proj     = (const float*)d_in[4];
    const float* bias_table = (const float*)d_in[5];
    const float* g1         = (const float*)d_in[6];
    const float* b1         = (const float*)d_in[7];
    const float* g2         = (const float*)d_in[8];
    const float* b2         = (const float*)d_in[9];
    const float* w_mlp      = (const float*)d_in[10];
    const float* b_mlp      = (const float*)d_in[11];

    char* ws = (char*)d_ws;
    unsigned short* bias_r = (unsigned short*)ws;                   //  15,925,248 B
    unsigned short* o_ws   = (unsigned short*)(ws + 15925248);      //  53,084,160 B
    unsigned short* w_t    = (unsigned short*)(ws + 69009408);      //     221,184 B
    unsigned short* wp_t   = (unsigned short*)(ws + 69230592);      //      73,728 B
    unsigned short* wm_t   = (unsigned short*)(ws + 69304320);      //      73,728 B
    // total ws use: 69,378,048 B

    wconv_all<<<720, 256, 0, stream>>>(w_qkv, w_proj, w_mlp, w_t, wp_t, wm_t);
    bias_reorg<<<324, 256, 0, stream>>>(bias_table, bias_r);
    qkattn<<<960, 384, 0, stream>>>(x, w_t, b_qkv, bias_r, o_ws);
    mlp_mfma<<<1080, 512, 0, stream>>>(o_ws, x, wp_t, b_proj, g1, b1, g2, b2,
                                       wm_t, b_mlp, (float*)d_out);
}

// Round 24
// 238.335 us; speedup vs baseline: 1.0941x; 1.0941x over previous
//
#include <hip/hip_runtime.h>
#include <hip/hip_bf16.h>

// EarthSpecificBlock, MI355X round 24 = EXACT REVERT to round 22 (240.1us,
// session best). r23's QSTR=44 broke 16B alignment of b128 LDS ops (88B row
// stride) and the bias prefetch stalled Phase A issue: conflicts 9.4M->3.8M
// but dur +20us -> conflicts are latency-hidden in this 2-phase shell.
// Final structure: fused per-window qkv+attn (6 waves, Xw staged from fp32,
// bias as MFMA C-operand, Q pre-scaled) + whole-weight-LDS mlp.

typedef __attribute__((ext_vector_type(8))) short bfrag;          // 8 bf16 (4 VGPR)
typedef __attribute__((ext_vector_type(4))) float f32x4;          // C/D frag
typedef __attribute__((ext_vector_type(4))) unsigned short us4;   // 8B of bf16
typedef __attribute__((ext_vector_type(8))) unsigned short us8;   // 16B of bf16

#define VSTR 172   // Vt row stride (ushorts); 168 caused 4-way write conflicts

__device__ __forceinline__ unsigned short f2bf(float f) {
    __hip_bfloat16 h = __float2bfloat16(f);     // HW RNE cvt
    unsigned short s;
    __builtin_memcpy(&s, &h, 2);
    return s;
}
__device__ __forceinline__ us4 pack4(float a, float b, float c, float d) {
    us4 o;
    o[0] = f2bf(a); o[1] = f2bf(b); o[2] = f2bf(c); o[3] = f2bf(d);
    return o;
}
__device__ __forceinline__ float bf2f(unsigned short s) {
    return __builtin_bit_cast(float, ((unsigned int)s) << 16);
}
__device__ __forceinline__ int token_of(int iw, int n) {
    int wi = iw % 15, hi = (iw / 15) % 16, zi = iw / 240;
    int ww = n % 12, hh = (n / 12) % 6, zz = n / 72;
    return ((zi * 2 + zz) * 96 + hi * 6 + hh) * 180 + wi * 12 + ww;
}

#define INV_SCALE 0.17677669529663687f   // 1/sqrt(32)

// ---- setup (merged): blocks 0..431 -> wt (Q rows pre-scaled);
// 432..575 -> wp_t; 576..719 -> wm_t. ----
__global__ __launch_bounds__(256) void wconv_all(const float* __restrict__ w_qkv,
                                                 const float* __restrict__ w_proj,
                                                 const float* __restrict__ w_mlp,
                                                 unsigned short* __restrict__ wt,
                                                 unsigned short* __restrict__ wp_t,
                                                 unsigned short* __restrict__ wm_t) {
    int b = blockIdx.x;
    if (b < 432) {
        int id = b * 256 + threadIdx.x;            // 110592
        if (id >= 110592) return;
        int k = id / 576, c = id - k * 576;
        float v = w_qkv[id];
        if (c < 192) v *= INV_SCALE;
        wt[c * 192 + k] = f2bf(v);
    } else {
        int y = (b - 432) / 144;                   // 0: wp, 1: wm
        int id = ((b - 432) - y * 144) * 256 + threadIdx.x;   // 36864
        if (id >= 36864) return;
        const float* src = y ? w_mlp : w_proj;
        unsigned short* dst = y ? wm_t : wp_t;
        int n = id / 192, k = id - n * 192;
        dst[id] = f2bf(src[(size_t)k * 192 + n]);
    }
}

// ---- bias_r[th][i][j] = bias_table[posidx(i,j)][t][h] (bf16) ----
__global__ __launch_bounds__(256) void bias_reorg(const float* __restrict__ bias_table,
                                                  unsigned short* __restrict__ bias_r) {
    __shared__ unsigned short T[384][68];
    int p0 = blockIdx.x * 64;                      // 324 blocks x 64 pairs
    int tid = threadIdx.x;
    for (int e = tid; e < 64 * 384; e += 256) {
        int pl = e / 384, th = e - pl * 384;
        int pair = p0 + pl;
        int i = pair / 144, j = pair - i * 144;
        int z1 = i / 72, h1 = (i / 12) % 6, w1 = i % 12;
        int z2 = j / 72, h2 = (j / 12) % 6, w2 = j % 12;
        int idx = (z1 + 2 * z2) * 828 + (h1 + 6 * h2) * 23 + (w1 - w2 + 11);
        T[th][pl] = f2bf(bias_table[(size_t)idx * 384 + th]);
    }
    __syncthreads();
    for (int e = tid; e < 384 * 16; e += 256) {
        int th = e >> 4, pc = e & 15;
        *(us4*)&bias_r[(size_t)th * 20736 + p0 + pc * 4] = *(const us4*)&T[th][pc * 4];
    }
}

// ---- Fused QKV + Attention, one block per WINDOW, 6 waves (r15/r18 shell).
// Xw staged from fp32 x (cvt in staging); 3 rounds x 2 heads; waves (tri,tw):
// tw = 0:Q 1:K 2:V. Phase A swapped operands; S MFMA takes bias as C-operand
// (Q weights pre-scaled). Phase B = attention body on buffers[tri]. ----
__global__ __launch_bounds__(384) void qkattn(const float* __restrict__ x,
                                              const unsigned short* __restrict__ wt,
                                              const float* __restrict__ b_qkv,
                                              const unsigned short* __restrict__ bias_r,
                                              unsigned short* __restrict__ o_ws) {
    __shared__ __align__(16) unsigned short Xw[144 * 200];      // 57600 B
    __shared__ __align__(16) unsigned short Ql[2][144 * 40];    // 23040 B (+Pb alias)
    __shared__ __align__(16) unsigned short Kl[2][144 * 40];    // 23040 B
    __shared__ __align__(16) unsigned short Vt[2][32 * VSTR];   // 22016 B (pad-172)
    int tid = threadIdx.x;
    int iw = blockIdx.x;
    int w = tid >> 6, l = tid & 63, li = l & 15, lg = l >> 4;
    int tri = w / 3, tw = w - tri * 3;

    // stage window x fp32 -> bf16 into Xw: 3456 chunks of 8 elems, 9/thread
#pragma unroll
    for (int i = 0; i < 9; ++i) {
        int idx = tid + i * 384;                   // < 3456 = 144*24
        int r = idx / 24, g = idx - r * 24;
        const float* xp = &x[(size_t)token_of(iw, r) * 192 + g * 8];
        float4 v0 = *(const float4*)xp;
        float4 v1 = *(const float4*)(xp + 4);
        us4 a = pack4(v0.x, v0.y, v0.z, v0.w);
        us4 b = pack4(v1.x, v1.y, v1.z, v1.w);
        *(us4*)&Xw[r * 200 + g * 8] = a;
        *(us4*)&Xw[r * 200 + g * 8 + 4] = b;
    }
    __syncthreads();

    for (int rnd = 0; rnd < 3; ++rnd) {
        int h = rnd * 2 + tri;

        // ---- Phase A: D[c][t] = sum_k W[k][c] X[t][k] (swapped operands) ----
        int wrow = tw * 192 + h * 32;
        f32x4 acc[2][9];
#pragma unroll
        for (int ct = 0; ct < 2; ++ct)
#pragma unroll
            for (int tt = 0; tt < 9; ++tt) acc[ct][tt] = (f32x4){0.f, 0.f, 0.f, 0.f};
#pragma unroll
        for (int kk = 0; kk < 6; ++kk) {
            int k0 = kk * 32 + lg * 8;
            bfrag wf[2];
#pragma unroll
            for (int ct = 0; ct < 2; ++ct)
                wf[ct] = *(const bfrag*)&wt[(size_t)(wrow + ct * 16 + li) * 192 + k0];
#pragma unroll
            for (int tt = 0; tt < 9; ++tt) {
                bfrag xf = *(const bfrag*)&Xw[(tt * 16 + li) * 200 + k0];
                acc[0][tt] = __builtin_amdgcn_mfma_f32_16x16x32_bf16(wf[0], xf, acc[0][tt], 0, 0, 0);
                acc[1][tt] = __builtin_amdgcn_mfma_f32_16x16x32_bf16(wf[1], xf, acc[1][tt], 0, 0, 0);
            }
        }
        // lane holds D[c = ct*16 + lg*4 + r][t = tt*16 + li]
        if (tw < 2) {
            unsigned short* dst = (tw == 0) ? &Ql[tri][0] : &Kl[tri][0];
            float bscale = (tw == 0) ? INV_SCALE : 1.0f;   // Q bias pre-scaled too
#pragma unroll
            for (int ct = 0; ct < 2; ++ct) {
                float4 bq = *(const float4*)&b_qkv[tw * 192 + h * 32 + ct * 16 + lg * 4];
                bq.x *= bscale; bq.y *= bscale; bq.z *= bscale; bq.w *= bscale;
#pragma unroll
                for (int tt = 0; tt < 9; ++tt) {
                    us4 o = pack4(acc[ct][tt][0] + bq.x, acc[ct][tt][1] + bq.y,
                                  acc[ct][tt][2] + bq.z, acc[ct][tt][3] + bq.w);
                    *(us4*)&dst[(tt * 16 + li) * 40 + ct * 16 + lg * 4] = o;
                }
            }
        } else {
#pragma unroll
            for (int ct = 0; ct < 2; ++ct) {
                float4 bq = *(const float4*)&b_qkv[2 * 192 + h * 32 + ct * 16 + lg * 4];
                float bqa[4] = {bq.x, bq.y, bq.z, bq.w};
#pragma unroll
                for (int tt = 0; tt < 9; ++tt)
#pragma unroll
                    for (int r = 0; r < 4; ++r)
                        Vt[tri][(ct * 16 + lg * 4 + r) * VSTR + tt * 16 + li] =
                            f2bf(acc[ct][tt][r] + bqa[r]);
            }
            // zero-pad Vt cols 144..159 (this wave owns its tri buffer)
            int d = l >> 1, half = l & 1;
            *(uint4*)&Vt[tri][d * VSTR + 144 + half * 8] = (uint4){0u, 0u, 0u, 0u};
        }
        __syncthreads();

        // ---- Phase B: attention (buffers [tri]) ----
        int it0 = tw * 3;
        unsigned short* Pbw = &Ql[tri][(size_t)tw * 48 * 40];
        bfrag qf[3];
#pragma unroll
        for (int itl = 0; itl < 3; ++itl)
            qf[itl] = *(const bfrag*)&Ql[tri][((it0 + itl) * 16 + li) * 40 + lg * 8];

        const unsigned short* bp = bias_r + ((size_t)((iw & 63) * 6 + h)) * 20736;
        // S^T = (scaled Q)K^T + bias, bias enters as the MFMA C-operand
        f32x4 S[9][3];
#pragma unroll
        for (int jt = 0; jt < 9; ++jt) {
            bfrag kf = *(const bfrag*)&Kl[tri][(jt * 16 + li) * 40 + lg * 8];
#pragma unroll
            for (int itl = 0; itl < 3; ++itl) {
                int i = (it0 + itl) * 16 + li;
                int j0 = jt * 16 + lg * 4;
                us4 bv = *(const us4*)&bp[i * 144 + j0];
                f32x4 c;
                c[0] = bf2f(bv[0]); c[1] = bf2f(bv[1]);
                c[2] = bf2f(bv[2]); c[3] = bf2f(bv[3]);
                S[jt][itl] = __builtin_amdgcn_mfma_f32_16x16x32_bf16(kf, qf[itl], c, 0, 0, 0);
            }
        }

        float inv[3];
#pragma unroll
        for (int itl = 0; itl < 3; ++itl) {
            float mx = -3.0e38f;
#pragma unroll
            for (int jt = 0; jt < 9; ++jt)
#pragma unroll
                for (int r = 0; r < 4; ++r) mx = fmaxf(mx, S[jt][itl][r]);
            mx = fmaxf(mx, __shfl_xor(mx, 16));
            mx = fmaxf(mx, __shfl_xor(mx, 32));
            float sum = 0.f;
#pragma unroll
            for (int jt = 0; jt < 9; ++jt)
#pragma unroll
                for (int r = 0; r < 4; ++r) {
                    float e = __expf(S[jt][itl][r] - mx);
                    S[jt][itl][r] = e;
                    sum += e;
                }
            sum += __shfl_xor(sum, 16);
            sum += __shfl_xor(sum, 32);
            inv[itl] = 1.f / sum;
        }

        f32x4 O[2][3];
#pragma unroll
        for (int dt = 0; dt < 2; ++dt)
#pragma unroll
            for (int itl = 0; itl < 3; ++itl) O[dt][itl] = (f32x4){0.f, 0.f, 0.f, 0.f};

        for (int jc = 0; jc < 5; ++jc) {
#pragma unroll
            for (int itl = 0; itl < 3; ++itl) {
                int irow = itl * 16 + li;
#pragma unroll
                for (int half = 0; half < 2; ++half) {
                    int jt = jc * 2 + half;
                    us4 pk;
                    if (jt < 9) {
                        pk = pack4(S[jt][itl][0], S[jt][itl][1], S[jt][itl][2], S[jt][itl][3]);
                    } else {
                        pk = (us4){0, 0, 0, 0};
                    }
                    *(us4*)&Pbw[irow * 40 + half * 16 + lg * 4] = pk;
                }
            }
            bfrag pf[3], af[2];
#pragma unroll
            for (int itl = 0; itl < 3; ++itl)
                pf[itl] = *(const bfrag*)&Pbw[(itl * 16 + li) * 40 + lg * 8];
#pragma unroll
            for (int dt = 0; dt < 2; ++dt)
                af[dt] = *(const bfrag*)&Vt[tri][(dt * 16 + li) * VSTR + jc * 32 + lg * 8];
#pragma unroll
            for (int dt = 0; dt < 2; ++dt)
#pragma unroll
                for (int itl = 0; itl < 3; ++itl)
                    O[dt][itl] = __builtin_amdgcn_mfma_f32_16x16x32_bf16(af[dt], pf[itl], O[dt][itl], 0, 0, 0);
        }

#pragma unroll
        for (int itl = 0; itl < 3; ++itl) {
#pragma unroll
            for (int dt = 0; dt < 2; ++dt) {
                us4 ov = pack4(O[dt][itl][0] * inv[itl], O[dt][itl][1] * inv[itl],
                               O[dt][itl][2] * inv[itl], O[dt][itl][3] * inv[itl]);
                *(us4*)&Pbw[(itl * 16 + li) * 40 + dt * 16 + lg * 4] = ov;
            }
        }
#pragma unroll
        for (int s = 0; s < 3; ++s) {
            int gi = s * 64 + l;
            int row = gi >> 2, g = gi & 3;
            uint4 v = *(const uint4*)&Pbw[row * 40 + g * 8];
            int t = token_of(iw, it0 * 16 + row);
            *(uint4*)&o_ws[(size_t)t * 192 + h * 32 + g * 8] = v;
        }
        __syncthreads();                           // buffers reusable next round
    }
}

// ---- Fused proj+LN1+res -> mlp+LN2+res. 128 rows/block, 8 waves.
// Whole weight matrix in LDS per GEMM; GEMM1 A direct from global. ----
__global__ __launch_bounds__(512) void mlp_mfma(const unsigned short* __restrict__ o_ws,
                                                const float* __restrict__ x,
                                                const unsigned short* __restrict__ wp_t,
                                                const float* __restrict__ b_proj,
                                                const float* __restrict__ g1,
                                                const float* __restrict__ b1,
                                                const float* __restrict__ g2,
                                                const float* __restrict__ b2,
                                                const unsigned short* __restrict__ wm_t,
                                                const float* __restrict__ b_mlp,
                                                float* __restrict__ out) {
    __shared__ __align__(16) unsigned short Al[128 * 200];  // 51200 B (x1 bf16)
    __shared__ __align__(16) unsigned short Bf[192 * 200];  // 76800 B (full weight [n][k])
    int tid = threadIdx.x;
    int t0 = blockIdx.x * 128;
    int w = tid >> 6, l = tid & 63, li = l & 15, lg = l >> 4;

#pragma unroll
    for (int i = 0; i < 9; ++i) {
        int idx = tid + i * 512;                 // < 4608
        int r = idx / 24, g = idx - r * 24;
        *(uint4*)&Bf[r * 200 + g * 8] = *(const uint4*)&wp_t[(size_t)r * 192 + g * 8];
    }
    __syncthreads();

    f32x4 C[12];
#pragma unroll
    for (int nt = 0; nt < 12; ++nt) C[nt] = (f32x4){0.f, 0.f, 0.f, 0.f};
    for (int kk = 0; kk < 6; ++kk) {
        int k0 = kk * 32 + lg * 8;
        bfrag a = *(const bfrag*)&o_ws[(size_t)(t0 + w * 16 + li) * 192 + k0];
#pragma unroll
        for (int nt = 0; nt < 12; ++nt) {
            bfrag b = *(const bfrag*)&Bf[(nt * 16 + li) * 200 + k0];
            C[nt] = __builtin_amdgcn_mfma_f32_16x16x32_bf16(a, b, C[nt], 0, 0, 0);
        }
    }
    __syncthreads();                             // all waves done reading Bf(wp)

#pragma unroll
    for (int i = 0; i < 9; ++i) {
        int idx = tid + i * 512;
        int r = idx / 24, g = idx - r * 24;
        *(uint4*)&Bf[r * 200 + g * 8] = *(const uint4*)&wm_t[(size_t)r * 192 + g * 8];
    }

    // LN1 + residual; C := x1 (f32); write bf16 x1 into Al (own wave's rows)
    {
        float bp[12], gg[12], bb[12];
#pragma unroll
        for (int nt = 0; nt < 12; ++nt) {
            int f = nt * 16 + li;
            bp[nt] = b_proj[f]; gg[nt] = g1[f]; bb[nt] = b1[f];
        }
#pragma unroll
        for (int r = 0; r < 4; ++r) {
            float s1 = 0.f;
#pragma unroll
            for (int nt = 0; nt < 12; ++nt) s1 += C[nt][r] + bp[nt];
            s1 += __shfl_xor(s1, 1); s1 += __shfl_xor(s1, 2);
            s1 += __shfl_xor(s1, 4); s1 += __shfl_xor(s1, 8);
            float mean = s1 * (1.f / 192.f);
            float s2 = 0.f;
#pragma unroll
            for (int nt = 0; nt < 12; ++nt) {
                float dv = C[nt][r] + bp[nt] - mean; s2 += dv * dv;
            }
            s2 += __shfl_xor(s2, 1); s2 += __shfl_xor(s2, 2);
            s2 += __shfl_xor(s2, 4); s2 += __shfl_xor(s2, 8);
            float rstd = rsqrtf(s2 * (1.f / 192.f) + 1e-5f);
            int row = w * 16 + lg * 4 + r;
            int t = t0 + row;
#pragma unroll
            for (int nt = 0; nt < 12; ++nt) {
                int f = nt * 16 + li;
                float ln = (C[nt][r] + bp[nt] - mean) * rstd * gg[nt] + bb[nt];
                float x1 = x[(size_t)t * 192 + f] + ln;
                C[nt][r] = x1;
                Al[row * 200 + f] = f2bf(x1);
            }
        }
    }
    __syncthreads();                             // Bf(wm) staged; Al x1 ready

    f32x4 C2[12];
#pragma unroll
    for (int nt = 0; nt < 12; ++nt) C2[nt] = (f32x4){0.f, 0.f, 0.f, 0.f};
    for (int kk = 0; kk < 6; ++kk) {
        int k0 = kk * 32 + lg * 8;
        bfrag a = *(const bfrag*)&Al[(w * 16 + li) * 200 + k0];
#pragma unroll
        for (int nt = 0; nt < 12; ++nt) {
            bfrag b = *(const bfrag*)&Bf[(nt * 16 + li) * 200 + k0];
            C2[nt] = __builtin_amdgcn_mfma_f32_16x16x32_bf16(a, b, C2[nt], 0, 0, 0);
        }
    }

    // LN2 + residual -> out (fp32)
    {
        float bp[12], gg[12], bb[12];
#pragma unroll
        for (int nt = 0; nt < 12; ++nt) {
            int f = nt * 16 + li;
            bp[nt] = b_mlp[f]; gg[nt] = g2[f]; bb[nt] = b2[f];
        }
#pragma unroll
        for (int r = 0; r < 4; ++r) {
            float s1 = 0.f;
#pragma unroll
            for (int nt = 0; nt < 12; ++nt) s1 += C2[nt][r] + bp[nt];
            s1 += __shfl_xor(s1, 1); s1 += __shfl_xor(s1, 2);
            s1 += __shfl_xor(s1, 4); s1 += __shfl_xor(s1, 8);
            float mean = s1 * (1.f / 192.f);
            float s2 = 0.f;
#pragma unroll
            for (int nt = 0; nt < 12; ++nt) {
                float dv = C2[nt][r] + bp[nt] - mean; s2 += dv * dv;
            }
            s2 += __shfl_xor(s2, 1); s2 += __shfl_xor(s2, 2);
            s2 += __shfl_xor(s2, 4); s2 += __shfl_xor(s2, 8);
            float rstd = rsqrtf(s2 * (1.f / 192.f) + 1e-5f);
            int t = t0 + w * 16 + lg * 4 + r;
#pragma unroll
            for (int nt = 0; nt < 12; ++nt) {
                int f = nt * 16 + li;
                float ln = (C2[nt][r] + bp[nt] - mean) * rstd * gg[nt] + bb[nt];
                out[(size_t)t * 192 + f] = C[nt][r] + ln;
            }
        }
    }
}

extern "C" void kernel_launch(void* const* d_in, const int* in_sizes, int n_in,
                              void* d_out, int out_size, void* d_ws, size_t ws_size,
                              hipStream_t stream) {
    const float* x          = (const float*)d_in[0];
    const float* w_qkv      = (const float*)d_in[1];
    const float* b_qkv      = (const float*)d_in[2];
    const float* w_proj     = (const float*)d_in[3];
    const float* b_proj     = (const float*)d_in[4];
    const float* bias_table = (const float*)d_in[5];
    const float* g1         = (const float*)d_in[6];
    const float* b1         = (const float*)d_in[7];
    const float* g2         = (const float*)d_in[8];
    const float* b2         = (const float*)d_in[9];
    const float* w_mlp      = (const float*)d_in[10];
    const float* b_mlp      = (const float*)d_in[11];

    char* ws = (char*)d_ws;
    unsigned short* bias_r = (unsigned short*)ws;                   //  15,925,248 B
    unsigned short* o_ws   = (unsigned short*)(ws + 15925248);      //  53,084,160 B
    unsigned short* w_t    = (unsigned short*)(ws + 69009408);      //     221,184 B
    unsigned short* wp_t   = (unsigned short*)(ws + 69230592);      //      73,728 B
    unsigned short* wm_t   = (unsigned short*)(ws + 69304320);      //      73,728 B
    // total ws use: 69,378,048 B

    wconv_all<<<720, 256, 0, stream>>>(w_qkv, w_proj, w_mlp, w_t, wp_t, wm_t);
    bias_reorg<<<324, 256, 0, stream>>>(bias_table, bias_r);
    qkattn<<<960, 384, 0, stream>>>(x, w_t, b_qkv, bias_r, o_ws);
    mlp_mfma<<<1080, 512, 0, stream>>>(o_ws, x, wp_t, b_proj, g1, b1, g2, b2,
                                       wm_t, b_mlp, (float*)d_out);
}